// Round 1
// baseline (480.763 us; speedup 1.0000x reference)
//
#include <hip/hip_runtime.h>

// Problem dims (fixed by reference)
#define NB     256    // batch
#define IN1    1024
#define H1     2048
#define OUT3   1024
#define TSTEPS 50

typedef __attribute__((ext_vector_type(8))) short short8;
typedef __attribute__((ext_vector_type(4))) float f32x4;

__device__ __forceinline__ unsigned short f2bf(float f) {
  unsigned u = __float_as_uint(f);
  u += 0x7FFFu + ((u >> 16) & 1u);   // round-to-nearest-even
  return (unsigned short)(u >> 16);
}
__device__ __forceinline__ float bf2f(unsigned short h) {
  return __uint_as_float(((unsigned)h) << 16);
}

__device__ __forceinline__ void gl2lds16(const void* g, void* l) {
  __builtin_amdgcn_global_load_lds(
      (const __attribute__((address_space(1))) unsigned char*)g,
      (__attribute__((address_space(3))) unsigned char*)l, 16, 0, 0);
}

// ---------------- W2 -> bf16 hi/lo split ----------------
__global__ __launch_bounds__(256)
void split_kernel(const float* __restrict__ W, unsigned short* __restrict__ hi,
                  unsigned short* __restrict__ lo, int n) {
  int i = blockIdx.x * 256 + threadIdx.x;
  if (i < n) {
    float w = W[i];
    unsigned short h = f2bf(w);
    hi[i] = h;
    lo[i] = f2bf(w - bf2f(h));
  }
}

// ---------------- layer-1 spike precompute ----------------
// each thread owns one (b,h); v1 dynamics independent of everything else
__global__ __launch_bounds__(256)
void sim1_kernel(const float* __restrict__ i1, unsigned short* __restrict__ s1all) {
  int idx = blockIdx.x * 256 + threadIdx.x;   // NB*H1 threads
  float inp = i1[idx];
  float v = 0.f;
  #pragma unroll
  for (int t = 0; t < TSTEPS; ++t) {
    v += inp;                                  // v1 = v1 + i1   (matches ref order)
    bool s = (v >= 1.0f);
    s1all[(size_t)t * (NB * H1) + idx] = s ? (unsigned short)0x3F80 : (unsigned short)0;
    if (s) v = 0.f;                            // v1 *= (1-s1)
  }
}

// ---------------- layer-2 membrane scan -> spike counts ----------------
__global__ __launch_bounds__(256)
void sim2_kernel(const float* __restrict__ A2, const float* __restrict__ b2,
                 float* __restrict__ v2s, float* __restrict__ cnt,
                 int tch, int init) {
  int idx = blockIdx.x * 256 + threadIdx.x;   // NB*H1 threads
  float v = init ? 0.f : v2s[idx];
  float c = init ? 0.f : cnt[idx];
  float bb = b2[idx & (H1 - 1)];
  for (int t = 0; t < tch; ++t) {
    v = v + A2[(size_t)t * (NB * H1) + idx];  // v2 + gemm
    v = v + bb;                               // + b2 (ref order)
    if (v >= 1.0f) { c += 1.f; v = 0.f; }
  }
  v2s[idx] = v;
  cnt[idx] = c;
}

// ---------------- simple fp32 TN GEMM: C = (A@B^T + bscale*bias)*oscale ----------------
// A [M][K] row-major, B [N][K] row-major, bias [N]
__global__ __launch_bounds__(256)
void gemm_f32_tn(const float* __restrict__ A, const float* __restrict__ B,
                 const float* __restrict__ bias, float* __restrict__ C,
                 int M, int N, int K, float bscale, float oscale) {
  __shared__ float As[16][68];
  __shared__ float Bs[16][68];
  const int t  = threadIdx.x;
  const int tx = t & 15, ty = t >> 4;
  const int m0 = blockIdx.y * 64, n0 = blockIdx.x * 64;
  const int lr = t >> 4, lk = t & 15;
  float acc[4][4] = {};
  for (int k0 = 0; k0 < K; k0 += 16) {
    #pragma unroll
    for (int i = 0; i < 4; ++i) {
      As[lk][lr + i * 16] = A[(size_t)(m0 + lr + i * 16) * K + k0 + lk];
      Bs[lk][lr + i * 16] = B[(size_t)(n0 + lr + i * 16) * K + k0 + lk];
    }
    __syncthreads();
    #pragma unroll
    for (int kk = 0; kk < 16; ++kk) {
      float4 a4 = *(const float4*)&As[kk][ty * 4];
      float4 b4 = *(const float4*)&Bs[kk][tx * 4];
      float av[4] = {a4.x, a4.y, a4.z, a4.w};
      float bv[4] = {b4.x, b4.y, b4.z, b4.w};
      #pragma unroll
      for (int i = 0; i < 4; ++i)
        #pragma unroll
        for (int j = 0; j < 4; ++j)
          acc[i][j] += av[i] * bv[j];
    }
    __syncthreads();
  }
  #pragma unroll
  for (int i = 0; i < 4; ++i) {
    int row = m0 + ty * 4 + i;
    #pragma unroll
    for (int j = 0; j < 4; ++j) {
      int col = n0 + tx * 4 + j;
      C[(size_t)row * N + col] = (acc[i][j] + bscale * bias[col]) * oscale;
    }
  }
}

// ---------------- bf16 hi/lo MFMA GEMM:  C[M][2048] = A @ (Whi+Wlo)^T ----------------
// A [M][2048] bf16-bits (spikes, exact), Bhi/Blo [2048][2048] bf16-bits
// m97-style: 128x128 tile, BK=32, 4 waves (2x2), 16x16x32 MFMA, global_load_lds w=16
__global__ __launch_bounds__(256)
void gemm2_mfma(const unsigned short* __restrict__ A,
                const unsigned short* __restrict__ Bhi,
                const unsigned short* __restrict__ Blo,
                float* __restrict__ C, int M) {
  __shared__ unsigned short As[128 * 32];
  __shared__ unsigned short Bs[128 * 32];
  const int t  = threadIdx.x;
  const int l  = t & 63;
  const int w  = t >> 6;
  const int wr = w >> 1, wc = w & 1;
  const int m0 = blockIdx.y * 128;
  const int n0 = blockIdx.x * 128;
  const int r  = t >> 2;          // 0..63 staging row within half-tile
  const int kf = (t & 3) * 8;     // staging k-offset (bf16 elems)
  const int lr = l & 15;          // fragment row/col
  const int lk = (l >> 4) * 8;    // fragment k-offset

  f32x4 acc[4][4];
  #pragma unroll
  for (int m = 0; m < 4; ++m)
    #pragma unroll
    for (int n = 0; n < 4; ++n)
      acc[m][n] = (f32x4)(0.f);

  const unsigned short* Bsel[2] = {Bhi, Blo};
  #pragma unroll 1
  for (int limb = 0; limb < 2; ++limb) {
    const unsigned short* Bsrc = Bsel[limb];
    #pragma unroll 1
    for (int ak = 0; ak < 2048; ak += 32) {
      // stage A-tile [128][32] and B-tile [128][32]; dest is linear (lane*16B) per wave
      gl2lds16(A    + (size_t)(m0 + r)       * 2048 + ak + kf, As + r * 32 + kf);
      gl2lds16(A    + (size_t)(m0 + 64 + r)  * 2048 + ak + kf, As + (64 + r) * 32 + kf);
      gl2lds16(Bsrc + (size_t)(n0 + r)       * 2048 + ak + kf, Bs + r * 32 + kf);
      gl2lds16(Bsrc + (size_t)(n0 + 64 + r)  * 2048 + ak + kf, Bs + (64 + r) * 32 + kf);
      __syncthreads();
      short8 af[4], bfr[4];
      #pragma unroll
      for (int m = 0; m < 4; ++m)
        af[m] = *(const short8*)(As + (wr * 64 + m * 16 + lr) * 32 + lk);
      #pragma unroll
      for (int n = 0; n < 4; ++n)
        bfr[n] = *(const short8*)(Bs + (wc * 64 + n * 16 + lr) * 32 + lk);
      #pragma unroll
      for (int m = 0; m < 4; ++m)
        #pragma unroll
        for (int n = 0; n < 4; ++n)
          acc[m][n] = __builtin_amdgcn_mfma_f32_16x16x32_bf16(af[m], bfr[n], acc[m][n], 0, 0, 0);
      __syncthreads();
    }
  }
  // epilogue: C/D layout col=lane&15, row=(lane>>4)*4+j  [m89-verified]
  const int crow = (l >> 4) * 4;
  #pragma unroll
  for (int m = 0; m < 4; ++m) {
    #pragma unroll
    for (int n = 0; n < 4; ++n) {
      int col  = n0 + wc * 64 + n * 16 + lr;
      int rowb = m0 + wr * 64 + m * 16 + crow;
      #pragma unroll
      for (int j = 0; j < 4; ++j)
        C[(size_t)(rowb + j) * 2048 + col] = acc[m][n][j];
    }
  }
}

extern "C" void kernel_launch(void* const* d_in, const int* in_sizes, int n_in,
                              void* d_out, int out_size, void* d_ws, size_t ws_size,
                              hipStream_t stream) {
  const float* x  = (const float*)d_in[0];
  const float* W1 = (const float*)d_in[1];
  const float* b1 = (const float*)d_in[2];
  const float* W2 = (const float*)d_in[3];
  const float* b2 = (const float*)d_in[4];
  const float* W3 = (const float*)d_in[5];
  const float* b3 = (const float*)d_in[6];
  float* out = (float*)d_out;

  char* ws = (char*)d_ws;
  size_t off = 0;
  auto take = [&](size_t bytes) -> void* {
    void* p = ws + off;
    off += (bytes + 255) & ~(size_t)255;
    return p;
  };
  unsigned short* W2hi  = (unsigned short*)take((size_t)H1 * H1 * 2);
  unsigned short* W2lo  = (unsigned short*)take((size_t)H1 * H1 * 2);
  float*          i1    = (float*)take((size_t)NB * H1 * 4);
  unsigned short* s1all = (unsigned short*)take((size_t)TSTEPS * NB * H1 * 2);
  float*          v2s   = (float*)take((size_t)NB * H1 * 4);
  float*          cnt   = (float*)take((size_t)NB * H1 * 4);

  const size_t plane = (size_t)NB * H1 * 4;   // one fp32 timestep plane (2 MB)
  size_t avail = (ws_size > off) ? (ws_size - off) : 0;
  int CH = (int)(avail / plane);
  if (CH > TSTEPS) CH = TSTEPS;
  if (CH < 1) CH = 1;
  float* A2 = (float*)take((size_t)CH * plane);

  // 1) split W2 into bf16 hi/lo limbs
  split_kernel<<<dim3((H1 * H1 + 255) / 256), 256, 0, stream>>>(W2, W2hi, W2lo, H1 * H1);

  // 2) i1 = x @ W1^T + b1   (fp32, computed once)
  gemm_f32_tn<<<dim3(H1 / 64, NB / 64), 256, 0, stream>>>(x, W1, b1, i1, NB, H1, IN1, 1.f, 1.f);

  // 3) all layer-1 spikes for all T timesteps (elementwise-independent)
  sim1_kernel<<<dim3(NB * H1 / 256), 256, 0, stream>>>(i1, s1all);

  // 4) A2[t] = s1[t] @ W2^T as ONE batched MFMA GEMM (hi+lo limbs), then v2 scan
  for (int c0 = 0; c0 < TSTEPS; c0 += CH) {
    int ch = (TSTEPS - c0 < CH) ? (TSTEPS - c0) : CH;
    gemm2_mfma<<<dim3(H1 / 128, ch * NB / 128), 256, 0, stream>>>(
        s1all + (size_t)c0 * NB * H1, W2hi, W2lo, A2, ch * NB);
    sim2_kernel<<<dim3(NB * H1 / 256), 256, 0, stream>>>(A2, b2, v2s, cnt, ch, c0 == 0);
  }

  // 5) out = (S2sum @ W3^T + T*b3) / T   (v3 never resets -> linear collapse)
  gemm_f32_tn<<<dim3(OUT3 / 64, NB / 64), 256, 0, stream>>>(
      cnt, W3, b3, out, NB, OUT3, H1, (float)TSTEPS, 1.0f / TSTEPS);
}

// Round 2
// 347.071 us; speedup vs baseline: 1.3852x; 1.3852x over previous
//
#include <hip/hip_runtime.h>

// Problem dims (fixed by reference)
#define NB     256    // batch
#define IN1    1024
#define H1     2048
#define OUT3   1024
#define TSTEPS 50

typedef __attribute__((ext_vector_type(8))) short short8;
typedef __attribute__((ext_vector_type(4))) float f32x4;

__device__ __forceinline__ unsigned short f2bf(float f) {
  unsigned u = __float_as_uint(f);
  u += 0x7FFFu + ((u >> 16) & 1u);   // round-to-nearest-even
  return (unsigned short)(u >> 16);
}
__device__ __forceinline__ float bf2f(unsigned short h) {
  return __uint_as_float(((unsigned)h) << 16);
}

__device__ __forceinline__ void gl2lds16(const void* g, void* l) {
  __builtin_amdgcn_global_load_lds(
      (const __attribute__((address_space(1))) unsigned char*)g,
      (__attribute__((address_space(3))) unsigned char*)l, 16, 0, 0);
}

// ---------------- fp32 -> bf16 hi/lo split ----------------
__global__ __launch_bounds__(256)
void split_kernel(const float* __restrict__ W, unsigned short* __restrict__ hi,
                  unsigned short* __restrict__ lo, int n) {
  int i = blockIdx.x * 256 + threadIdx.x;
  if (i < n) {
    float w = W[i];
    unsigned short h = f2bf(w);
    hi[i] = h;
    lo[i] = f2bf(w - bf2f(h));
  }
}

// ---------------- fp32 -> bf16 (exact for small ints) ----------------
__global__ __launch_bounds__(256)
void cvt_bf_kernel(const float* __restrict__ in, unsigned short* __restrict__ out, int n) {
  int i = blockIdx.x * 256 + threadIdx.x;
  if (i < n) out[i] = f2bf(in[i]);
}

// ---------------- layer-1 spike precompute ----------------
__global__ __launch_bounds__(256)
void sim1_kernel(const float* __restrict__ i1, unsigned short* __restrict__ s1all) {
  int idx = blockIdx.x * 256 + threadIdx.x;   // NB*H1 threads
  float inp = i1[idx];
  float v = 0.f;
  #pragma unroll
  for (int t = 0; t < TSTEPS; ++t) {
    v += inp;
    bool s = (v >= 1.0f);
    s1all[(size_t)t * (NB * H1) + idx] = s ? (unsigned short)0x3F80 : (unsigned short)0;
    if (s) v = 0.f;
  }
}

// ---------------- layer-2 membrane scan -> spike counts ----------------
__global__ __launch_bounds__(256)
void sim2_kernel(const float* __restrict__ A2, const float* __restrict__ b2,
                 float* __restrict__ v2s, float* __restrict__ cnt,
                 int tch, int init) {
  int idx = blockIdx.x * 256 + threadIdx.x;   // NB*H1 threads
  float v = init ? 0.f : v2s[idx];
  float c = init ? 0.f : cnt[idx];
  float bb = b2[idx & (H1 - 1)];
  for (int t = 0; t < tch; ++t) {
    v = v + A2[(size_t)t * (NB * H1) + idx];
    v = v + bb;
    if (v >= 1.0f) { c += 1.f; v = 0.f; }
  }
  v2s[idx] = v;
  cnt[idx] = c;
}

// ---------------- generalized bf16 limb MFMA GEMM ----------------
// C[M][N] = (A0 @ B0^T) [+ A0@B1^T if BLO] [+ A1@B0^T if ALO], fp32 accum
// + optional bias: C = (acc + bscale*bias[col]) * oscale
// 128x128 tile, BK=64, 4 waves (2x2), 16x16x32 MFMA, global_load_lds w=16.
// LDS XOR-swizzle (T2, rule #21): linear LDS dest, pre-swizzled global source,
// XOR'd ds_read (xor mask = lane&7 is per-lane constant).
// XCD-bijective blockIdx swizzle (T1) when nwg%8==0.
template<bool ALO, bool BLO>
__global__ __launch_bounds__(256)
void gemm_mfma(const unsigned short* __restrict__ A0,
               const unsigned short* __restrict__ A1,
               const unsigned short* __restrict__ B0,
               const unsigned short* __restrict__ B1,
               const float* __restrict__ bias, float* __restrict__ C,
               int M, int N, int K, float bscale, float oscale) {
  __shared__ unsigned short As[(ALO ? 2 : 1) * 128 * 64];
  __shared__ unsigned short Bs[(BLO ? 2 : 1) * 128 * 64];

  // T1: XCD-aware contiguous-chunk swizzle (bijective when nwg%8==0)
  const int gx  = gridDim.x;
  const int nwg = gx * gridDim.y;
  int wg = blockIdx.y * gx + blockIdx.x;
  if ((nwg & 7) == 0) wg = (wg & 7) * (nwg >> 3) + (wg >> 3);
  const int bx = wg % gx, by = wg / gx;
  const int m0 = by * 128, n0 = bx * 128;

  const int t  = threadIdx.x;
  const int l  = t & 63;
  const int w  = t >> 6;
  const int wr = w >> 1, wc = w & 1;
  const int lr = l & 15;             // fragment row/col within 16
  const int kx = lr & 7;             // T2 read-side XOR (per-lane constant)
  // staging decomposition: thread t handles row r8(+32i), 16B-chunk c8
  const int r8   = t >> 3, c8 = t & 7;
  const int scol = (c8 ^ (r8 & 7)) * 8;   // pre-swizzled source column (bf16 elems)

  f32x4 acc[4][4];
  #pragma unroll
  for (int m = 0; m < 4; ++m)
    #pragma unroll
    for (int n = 0; n < 4; ++n)
      acc[m][n] = (f32x4)(0.f);

  #pragma unroll 1
  for (int k0 = 0; k0 < K; k0 += 64) {
    // ---- stage tiles (linear LDS dest = t*16B per round; swizzled source) ----
    #pragma unroll
    for (int i = 0; i < 4; ++i) {
      int row = i * 32 + r8;
      gl2lds16(A0 + (size_t)(m0 + row) * K + k0 + scol, As + row * 64 + c8 * 8);
    }
    if (ALO) {
      #pragma unroll
      for (int i = 0; i < 4; ++i) {
        int row = i * 32 + r8;
        gl2lds16(A1 + (size_t)(m0 + row) * K + k0 + scol, As + 128 * 64 + row * 64 + c8 * 8);
      }
    }
    #pragma unroll
    for (int i = 0; i < 4; ++i) {
      int row = i * 32 + r8;
      gl2lds16(B0 + (size_t)(n0 + row) * K + k0 + scol, Bs + row * 64 + c8 * 8);
    }
    if (BLO) {
      #pragma unroll
      for (int i = 0; i < 4; ++i) {
        int row = i * 32 + r8;
        gl2lds16(B1 + (size_t)(n0 + row) * K + k0 + scol, Bs + 128 * 64 + row * 64 + c8 * 8);
      }
    }
    __syncthreads();

    // ---- compute: 2 k-substeps x 16 frag-pairs x (1+BLO+ALO) products ----
    #pragma unroll
    for (int ks = 0; ks < 2; ++ks) {
      const int kc = ks * 4 + (l >> 4);          // logical 16B k-chunk 0..7
      const int ko = (kc ^ kx) * 8;              // swizzled k offset (bf16 elems)
      short8 a0f[4], b0f[4];
      #pragma unroll
      for (int m = 0; m < 4; ++m)
        a0f[m] = *(const short8*)(As + (wr * 64 + m * 16 + lr) * 64 + ko);
      #pragma unroll
      for (int n = 0; n < 4; ++n)
        b0f[n] = *(const short8*)(Bs + (wc * 64 + n * 16 + lr) * 64 + ko);
      #pragma unroll
      for (int m = 0; m < 4; ++m)
        #pragma unroll
        for (int n = 0; n < 4; ++n)
          acc[m][n] = __builtin_amdgcn_mfma_f32_16x16x32_bf16(a0f[m], b0f[n], acc[m][n], 0, 0, 0);
      if (BLO) {
        short8 b1f[4];
        #pragma unroll
        for (int n = 0; n < 4; ++n)
          b1f[n] = *(const short8*)(Bs + 128 * 64 + (wc * 64 + n * 16 + lr) * 64 + ko);
        #pragma unroll
        for (int m = 0; m < 4; ++m)
          #pragma unroll
          for (int n = 0; n < 4; ++n)
            acc[m][n] = __builtin_amdgcn_mfma_f32_16x16x32_bf16(a0f[m], b1f[n], acc[m][n], 0, 0, 0);
      }
      if (ALO) {
        short8 a1f[4];
        #pragma unroll
        for (int m = 0; m < 4; ++m)
          a1f[m] = *(const short8*)(As + 128 * 64 + (wr * 64 + m * 16 + lr) * 64 + ko);
        #pragma unroll
        for (int m = 0; m < 4; ++m)
          #pragma unroll
          for (int n = 0; n < 4; ++n)
            acc[m][n] = __builtin_amdgcn_mfma_f32_16x16x32_bf16(a1f[m], b0f[n], acc[m][n], 0, 0, 0);
      }
    }
    __syncthreads();
  }

  // epilogue: C/D layout col=lane&15, row=(lane>>4)*4+j  [m89-verified]
  const int crow = (l >> 4) * 4;
  #pragma unroll
  for (int m = 0; m < 4; ++m) {
    #pragma unroll
    for (int n = 0; n < 4; ++n) {
      int col  = n0 + wc * 64 + n * 16 + lr;
      int rowb = m0 + wr * 64 + m * 16 + crow;
      float bv = bias ? bscale * bias[col] : 0.f;
      #pragma unroll
      for (int j = 0; j < 4; ++j)
        C[(size_t)(rowb + j) * N + col] = (acc[m][n][j] + bv) * oscale;
    }
  }
}

extern "C" void kernel_launch(void* const* d_in, const int* in_sizes, int n_in,
                              void* d_out, int out_size, void* d_ws, size_t ws_size,
                              hipStream_t stream) {
  const float* x  = (const float*)d_in[0];
  const float* W1 = (const float*)d_in[1];
  const float* b1 = (const float*)d_in[2];
  const float* W2 = (const float*)d_in[3];
  const float* b2 = (const float*)d_in[4];
  const float* W3 = (const float*)d_in[5];
  const float* b3 = (const float*)d_in[6];
  float* out = (float*)d_out;

  char* ws = (char*)d_ws;
  size_t off = 0;
  auto take = [&](size_t bytes) -> void* {
    void* p = ws + off;
    off += (bytes + 255) & ~(size_t)255;
    return p;
  };
  unsigned short* W2hi  = (unsigned short*)take((size_t)H1 * H1 * 2);
  unsigned short* W2lo  = (unsigned short*)take((size_t)H1 * H1 * 2);
  unsigned short* W1hi  = (unsigned short*)take((size_t)H1 * IN1 * 2);
  unsigned short* W1lo  = (unsigned short*)take((size_t)H1 * IN1 * 2);
  unsigned short* W3hi  = (unsigned short*)take((size_t)OUT3 * H1 * 2);
  unsigned short* W3lo  = (unsigned short*)take((size_t)OUT3 * H1 * 2);
  unsigned short* xhi   = (unsigned short*)take((size_t)NB * IN1 * 2);
  unsigned short* xlo   = (unsigned short*)take((size_t)NB * IN1 * 2);
  float*          i1    = (float*)take((size_t)NB * H1 * 4);
  unsigned short* s1all = (unsigned short*)take((size_t)TSTEPS * NB * H1 * 2);
  float*          v2s   = (float*)take((size_t)NB * H1 * 4);
  float*          cnt   = (float*)take((size_t)NB * H1 * 4);
  unsigned short* cntbf = (unsigned short*)take((size_t)NB * H1 * 2);

  const size_t plane = (size_t)NB * H1 * 4;   // one fp32 timestep plane (2 MB)
  size_t avail = (ws_size > off) ? (ws_size - off) : 0;
  int CH = (int)(avail / plane);
  if (CH > TSTEPS) CH = TSTEPS;
  if (CH < 1) CH = 1;
  float* A2 = (float*)take((size_t)CH * plane);

  // 1) bf16 hi/lo limb splits
  split_kernel<<<dim3((H1 * H1 + 255) / 256), 256, 0, stream>>>(W2, W2hi, W2lo, H1 * H1);
  split_kernel<<<dim3((H1 * IN1 + 255) / 256), 256, 0, stream>>>(W1, W1hi, W1lo, H1 * IN1);
  split_kernel<<<dim3((OUT3 * H1 + 255) / 256), 256, 0, stream>>>(W3, W3hi, W3lo, OUT3 * H1);
  split_kernel<<<dim3((NB * IN1 + 255) / 256), 256, 0, stream>>>(x, xhi, xlo, NB * IN1);

  // 2) i1 = x @ W1^T + b1  (3 limb products: hi*hi + hi*lo + lo*hi)
  gemm_mfma<true, true><<<dim3(H1 / 128, NB / 128), 256, 0, stream>>>(
      xhi, xlo, W1hi, W1lo, b1, i1, NB, H1, IN1, 1.f, 1.f);

  // 3) all layer-1 spikes for all T timesteps (elementwise-independent)
  sim1_kernel<<<dim3(NB * H1 / 256), 256, 0, stream>>>(i1, s1all);

  // 4) A2[t] = s1[t] @ W2^T, both limbs in ONE K-pass; then v2 scan
  for (int c0 = 0; c0 < TSTEPS; c0 += CH) {
    int ch = (TSTEPS - c0 < CH) ? (TSTEPS - c0) : CH;
    gemm_mfma<false, true><<<dim3(H1 / 128, ch * NB / 128), 256, 0, stream>>>(
        s1all + (size_t)c0 * NB * H1, nullptr, W2hi, W2lo, nullptr, A2,
        ch * NB, H1, H1, 0.f, 1.f);
    sim2_kernel<<<dim3(NB * H1 / 256), 256, 0, stream>>>(A2, b2, v2s, cnt, ch, c0 == 0);
  }

  // 5) out = (cnt @ W3^T + T*b3) / T   (cnt integer <=50: exact in bf16)
  cvt_bf_kernel<<<dim3(NB * H1 / 256), 256, 0, stream>>>(cnt, cntbf, NB * H1);
  gemm_mfma<false, true><<<dim3(OUT3 / 128, NB / 128), 256, 0, stream>>>(
      cntbf, nullptr, W3hi, W3lo, b3, out, NB, OUT3, H1, (float)TSTEPS, 1.0f / TSTEPS);
}

// Round 3
// 298.973 us; speedup vs baseline: 1.6080x; 1.1609x over previous
//
#include <hip/hip_runtime.h>

// Problem dims (fixed by reference)
#define NB     256    // batch
#define IN1    1024
#define H1     2048
#define OUT3   1024
#define TSTEPS 50
#define KSPLIT 4

typedef __attribute__((ext_vector_type(8))) short short8;
typedef __attribute__((ext_vector_type(4))) float f32x4;

__device__ __forceinline__ unsigned short f2bf(float f) {
  unsigned u = __float_as_uint(f);
  u += 0x7FFFu + ((u >> 16) & 1u);   // round-to-nearest-even
  return (unsigned short)(u >> 16);
}
__device__ __forceinline__ float bf2f(unsigned short h) {
  return __uint_as_float(((unsigned)h) << 16);
}

__device__ __forceinline__ void gl2lds16(const void* g, void* l) {
  __builtin_amdgcn_global_load_lds(
      (const __attribute__((address_space(1))) unsigned char*)g,
      (__attribute__((address_space(3))) unsigned char*)l, 16, 0, 0);
}

// ---------------- fp32 -> bf16 hi/lo split (W2 only) ----------------
__global__ __launch_bounds__(256)
void split_kernel(const float* __restrict__ W, unsigned short* __restrict__ hi,
                  unsigned short* __restrict__ lo, int n) {
  int i = blockIdx.x * 256 + threadIdx.x;
  if (i < n) {
    float w = W[i];
    unsigned short h = f2bf(w);
    hi[i] = h;
    lo[i] = f2bf(w - bf2f(h));
  }
}

// ---------------- fp32 split-K SGEMM: P[z] = A[:,zKc:(z+1)Kc] @ B[:,...]^T ----------------
// A [M][K], B [N][K] row-major. 64x64 tile, 256 threads, grid (N/64, M/64, KSPLIT).
// Deterministic: partials reduced later in fixed order.
__global__ __launch_bounds__(256)
void sgemm_splitk(const float* __restrict__ A, const float* __restrict__ B,
                  float* __restrict__ P, int M, int N, int K) {
  __shared__ float As[16][68];
  __shared__ float Bs[16][68];
  const int t  = threadIdx.x;
  const int tx = t & 15, ty = t >> 4;
  const int m0 = blockIdx.y * 64, n0 = blockIdx.x * 64;
  const int Kc = K / KSPLIT;
  const int kbeg = blockIdx.z * Kc, kend = kbeg + Kc;
  const int lr = t >> 4, lk = t & 15;
  float acc[4][4] = {};
  for (int k0 = kbeg; k0 < kend; k0 += 16) {
    #pragma unroll
    for (int i = 0; i < 4; ++i) {
      As[lk][lr + i * 16] = A[(size_t)(m0 + lr + i * 16) * K + k0 + lk];
      Bs[lk][lr + i * 16] = B[(size_t)(n0 + lr + i * 16) * K + k0 + lk];
    }
    __syncthreads();
    #pragma unroll
    for (int kk = 0; kk < 16; ++kk) {
      float4 a4 = *(const float4*)&As[kk][ty * 4];
      float4 b4 = *(const float4*)&Bs[kk][tx * 4];
      float av[4] = {a4.x, a4.y, a4.z, a4.w};
      float bv[4] = {b4.x, b4.y, b4.z, b4.w};
      #pragma unroll
      for (int i = 0; i < 4; ++i)
        #pragma unroll
        for (int j = 0; j < 4; ++j)
          acc[i][j] += av[i] * bv[j];
    }
    __syncthreads();
  }
  float* Pp = P + (size_t)blockIdx.z * M * N;
  #pragma unroll
  for (int i = 0; i < 4; ++i)
    #pragma unroll
    for (int j = 0; j < 4; ++j)
      Pp[(size_t)(m0 + ty * 4 + i) * N + n0 + tx * 4 + j] = acc[i][j];
}

// ---------------- layer-1: reduce partials + spike precompute ----------------
__global__ __launch_bounds__(256)
void sim1_kernel(const float* __restrict__ P, const float* __restrict__ b1,
                 unsigned short* __restrict__ s1all) {
  int idx = blockIdx.x * 256 + threadIdx.x;   // NB*H1 threads
  float inp = b1[idx & (H1 - 1)];
  #pragma unroll
  for (int s = 0; s < KSPLIT; ++s) inp += P[(size_t)s * (NB * H1) + idx];
  float v = 0.f;
  #pragma unroll
  for (int t = 0; t < TSTEPS; ++t) {
    v += inp;
    bool s = (v >= 1.0f);
    s1all[(size_t)t * (NB * H1) + idx] = s ? (unsigned short)0x3F80 : (unsigned short)0;
    if (s) v = 0.f;
  }
}

// ---------------- layer-2 membrane scan -> spike counts ----------------
__global__ __launch_bounds__(256)
void sim2_kernel(const float* __restrict__ A2, const float* __restrict__ b2,
                 float* __restrict__ v2s, float* __restrict__ cnt,
                 int tch, int init) {
  int idx = blockIdx.x * 256 + threadIdx.x;   // NB*H1 threads
  float v = init ? 0.f : v2s[idx];
  float c = init ? 0.f : cnt[idx];
  float bb = b2[idx & (H1 - 1)];
  for (int t = 0; t < tch; ++t) {
    v = v + A2[(size_t)t * (NB * H1) + idx];
    v = v + bb;
    if (v >= 1.0f) { c += 1.f; v = 0.f; }
  }
  v2s[idx] = v;
  cnt[idx] = c;
}

// ---------------- layer-3 epilogue: out = (sum(P) + T*b3)/T ----------------
__global__ __launch_bounds__(256)
void out_epi_kernel(const float* __restrict__ P, const float* __restrict__ b3,
                    float* __restrict__ out) {
  int idx = blockIdx.x * 256 + threadIdx.x;   // NB*OUT3 threads
  float a = 0.f;
  #pragma unroll
  for (int s = 0; s < KSPLIT; ++s) a += P[(size_t)s * (NB * OUT3) + idx];
  out[idx] = (a + (float)TSTEPS * b3[idx & (OUT3 - 1)]) * (1.0f / TSTEPS);
}

// ---------------- bf16 dual-limb MFMA GEMM (layer 2) ----------------
// C[M][N] = A0 @ B0^T + A0 @ B1^T, fp32 accum.
// 128x128 tile, BK=64, 4 waves (2x2), 16x16x32 MFMA, global_load_lds w=16.
// LDS XOR-swizzle (T2, rule #21): linear LDS dest, pre-swizzled global source,
// XOR'd ds_read. XCD-bijective blockIdx swizzle (T1) when nwg%8==0.
__global__ __launch_bounds__(256)
void gemm_mfma(const unsigned short* __restrict__ A0,
               const unsigned short* __restrict__ B0,
               const unsigned short* __restrict__ B1,
               float* __restrict__ C, int M, int N, int K) {
  __shared__ unsigned short As[128 * 64];
  __shared__ unsigned short Bs[2 * 128 * 64];

  // T1: XCD-aware contiguous-chunk swizzle (bijective when nwg%8==0)
  const int gx  = gridDim.x;
  const int nwg = gx * gridDim.y;
  int wg = blockIdx.y * gx + blockIdx.x;
  if ((nwg & 7) == 0) wg = (wg & 7) * (nwg >> 3) + (wg >> 3);
  const int bx = wg % gx, by = wg / gx;
  const int m0 = by * 128, n0 = bx * 128;

  const int t  = threadIdx.x;
  const int l  = t & 63;
  const int w  = t >> 6;
  const int wr = w >> 1, wc = w & 1;
  const int lr = l & 15;             // fragment row/col within 16
  const int kx = lr & 7;             // T2 read-side XOR (per-lane constant)
  // staging decomposition: thread t handles row r8(+32i), 16B-chunk c8
  const int r8   = t >> 3, c8 = t & 7;
  const int scol = (c8 ^ (r8 & 7)) * 8;   // pre-swizzled source column (bf16 elems)

  f32x4 acc[4][4];
  #pragma unroll
  for (int m = 0; m < 4; ++m)
    #pragma unroll
    for (int n = 0; n < 4; ++n)
      acc[m][n] = (f32x4)(0.f);

  #pragma unroll 1
  for (int k0 = 0; k0 < K; k0 += 64) {
    // ---- stage tiles (linear LDS dest; swizzled global source) ----
    #pragma unroll
    for (int i = 0; i < 4; ++i) {
      int row = i * 32 + r8;
      gl2lds16(A0 + (size_t)(m0 + row) * K + k0 + scol, As + row * 64 + c8 * 8);
    }
    #pragma unroll
    for (int i = 0; i < 4; ++i) {
      int row = i * 32 + r8;
      gl2lds16(B0 + (size_t)(n0 + row) * K + k0 + scol, Bs + row * 64 + c8 * 8);
    }
    #pragma unroll
    for (int i = 0; i < 4; ++i) {
      int row = i * 32 + r8;
      gl2lds16(B1 + (size_t)(n0 + row) * K + k0 + scol, Bs + 128 * 64 + row * 64 + c8 * 8);
    }
    __syncthreads();

    // ---- compute: 2 k-substeps x 16 frag-pairs x 2 limb products ----
    #pragma unroll
    for (int ks = 0; ks < 2; ++ks) {
      const int kc = ks * 4 + (l >> 4);          // logical 16B k-chunk 0..7
      const int ko = (kc ^ kx) * 8;              // swizzled k offset (bf16 elems)
      short8 a0f[4], b0f[4], b1f[4];
      #pragma unroll
      for (int m = 0; m < 4; ++m)
        a0f[m] = *(const short8*)(As + (wr * 64 + m * 16 + lr) * 64 + ko);
      #pragma unroll
      for (int n = 0; n < 4; ++n)
        b0f[n] = *(const short8*)(Bs + (wc * 64 + n * 16 + lr) * 64 + ko);
      #pragma unroll
      for (int m = 0; m < 4; ++m)
        #pragma unroll
        for (int n = 0; n < 4; ++n)
          acc[m][n] = __builtin_amdgcn_mfma_f32_16x16x32_bf16(a0f[m], b0f[n], acc[m][n], 0, 0, 0);
      #pragma unroll
      for (int n = 0; n < 4; ++n)
        b1f[n] = *(const short8*)(Bs + 128 * 64 + (wc * 64 + n * 16 + lr) * 64 + ko);
      #pragma unroll
      for (int m = 0; m < 4; ++m)
        #pragma unroll
        for (int n = 0; n < 4; ++n)
          acc[m][n] = __builtin_amdgcn_mfma_f32_16x16x32_bf16(a0f[m], b1f[n], acc[m][n], 0, 0, 0);
    }
    __syncthreads();
  }

  // epilogue: C/D layout col=lane&15, row=(lane>>4)*4+j  [m89-verified]
  const int crow = (l >> 4) * 4;
  #pragma unroll
  for (int m = 0; m < 4; ++m) {
    #pragma unroll
    for (int n = 0; n < 4; ++n) {
      int col  = n0 + wc * 64 + n * 16 + lr;
      int rowb = m0 + wr * 64 + m * 16 + crow;
      #pragma unroll
      for (int j = 0; j < 4; ++j)
        C[(size_t)(rowb + j) * N + col] = acc[m][n][j];
    }
  }
}

extern "C" void kernel_launch(void* const* d_in, const int* in_sizes, int n_in,
                              void* d_out, int out_size, void* d_ws, size_t ws_size,
                              hipStream_t stream) {
  const float* x  = (const float*)d_in[0];
  const float* W1 = (const float*)d_in[1];
  const float* b1 = (const float*)d_in[2];
  const float* W2 = (const float*)d_in[3];
  const float* b2 = (const float*)d_in[4];
  const float* W3 = (const float*)d_in[5];
  const float* b3 = (const float*)d_in[6];
  float* out = (float*)d_out;

  char* ws = (char*)d_ws;
  size_t off = 0;
  auto take = [&](size_t bytes) -> void* {
    void* p = ws + off;
    off += (bytes + 255) & ~(size_t)255;
    return p;
  };
  unsigned short* W2hi  = (unsigned short*)take((size_t)H1 * H1 * 2);
  unsigned short* W2lo  = (unsigned short*)take((size_t)H1 * H1 * 2);
  unsigned short* s1all = (unsigned short*)take((size_t)TSTEPS * NB * H1 * 2);
  float*          v2s   = (float*)take((size_t)NB * H1 * 4);
  float*          cnt   = (float*)take((size_t)NB * H1 * 4);
  float*          Part  = (float*)take((size_t)KSPLIT * NB * H1 * 4);  // split-K partials

  const size_t plane = (size_t)NB * H1 * 4;   // one fp32 timestep plane (2 MB)
  size_t avail = (ws_size > off) ? (ws_size - off) : 0;
  int CH = (int)(avail / plane);
  if (CH > TSTEPS) CH = TSTEPS;
  if (CH < 1) CH = 1;
  float* A2 = (float*)take((size_t)CH * plane);

  // 1) W2 bf16 hi/lo limbs
  split_kernel<<<dim3((H1 * H1 + 255) / 256), 256, 0, stream>>>(W2, W2hi, W2lo, H1 * H1);

  // 2) layer 1 in fp32: P[z] = x @ W1[:,chunk]^T  (512 blocks), reduce fused in sim1
  sgemm_splitk<<<dim3(H1 / 64, NB / 64, KSPLIT), 256, 0, stream>>>(
      x, W1, Part, NB, H1, IN1);

  // 3) all layer-1 spikes for all T timesteps (elementwise-independent)
  sim1_kernel<<<dim3(NB * H1 / 256), 256, 0, stream>>>(Part, b1, s1all);

  // 4) A2[t] = s1[t] @ W2^T, both limbs in ONE K-pass; then v2 scan
  for (int c0 = 0; c0 < TSTEPS; c0 += CH) {
    int ch = (TSTEPS - c0 < CH) ? (TSTEPS - c0) : CH;
    gemm_mfma<<<dim3(H1 / 128, ch * NB / 128), 256, 0, stream>>>(
        s1all + (size_t)c0 * NB * H1, W2hi, W2lo, A2, ch * NB, H1, H1);
    sim2_kernel<<<dim3(NB * H1 / 256), 256, 0, stream>>>(A2, b2, v2s, cnt, ch, c0 == 0);
  }

  // 5) layer 3 in fp32: P[z] = cnt @ W3[:,chunk]^T (256 blocks) + epilogue
  sgemm_splitk<<<dim3(OUT3 / 64, NB / 64, KSPLIT), 256, 0, stream>>>(
      cnt, W3, Part, NB, OUT3, H1);
  out_epi_kernel<<<dim3(NB * OUT3 / 256), 256, 0, stream>>>(Part, b3, out);
}